// Round 1
// baseline (237.230 us; speedup 1.0000x reference)
//
#include <hip/hip_runtime.h>

// Problem dims (fixed by setup_inputs): T=1024, B=8, d=64, n=64
#define T_DIM 1024
#define B_DIM 8
#define D_DIM 64
#define N_DIM 64

// ---------------------------------------------------------------------------
// Kernel 1: per (b,n) scan line, compute w[t,b,n] = k[t,b,n] * decay[t,b,n]
//   decay[t] = expf(cumsum_t(log max(alpha,1e-8))) / (expf(total) + 1e-8)
// Block = one (b,n) pair, 256 threads, 4 timesteps per thread.
// Block-wide inclusive scan: wave shfl-scan + LDS cross-wave offsets.
// ---------------------------------------------------------------------------
__global__ __launch_bounds__(256) void decay_w_kernel(
    const float* __restrict__ kk, const float* __restrict__ alpha,
    float* __restrict__ w) {
  const int b = blockIdx.x >> 6;   // 0..7
  const int n = blockIdx.x & 63;   // 0..63
  const int tid = threadIdx.x;     // 0..255
  constexpr int TPT = T_DIM / 256; // 4 timesteps per thread
  const int t0 = tid * TPT;

  float la[TPT];
  float local = 0.f;
#pragma unroll
  for (int i = 0; i < TPT; ++i) {
    const size_t idx = ((size_t)(t0 + i) * B_DIM + b) * N_DIM + n;
    la[i] = logf(fmaxf(alpha[idx], 1e-8f));
    local += la[i];
  }

  // inclusive scan of `local` within the wave (64 lanes)
  float s = local;
#pragma unroll
  for (int off = 1; off < 64; off <<= 1) {
    float up = __shfl_up(s, off, 64);
    if ((tid & 63) >= off) s += up;
  }

  __shared__ float wsum[4];
  if ((tid & 63) == 63) wsum[tid >> 6] = s;
  __syncthreads();

  float woff = 0.f, total = 0.f;
#pragma unroll
  for (int wv = 0; wv < 4; ++wv) {
    const float t = wsum[wv];
    if (wv < (tid >> 6)) woff += t;
    total += t;
  }

  // denom: matches reference f32 behavior (expf(total) underflows to 0 -> 1e-8)
  const float denom = expf(total) + 1e-8f;
  const float inv_denom = 1.0f / denom;

  float cum = (s - local) + woff;  // exclusive prefix before this thread's chunk
#pragma unroll
  for (int i = 0; i < TPT; ++i) {
    cum += la[i];
    const float decay = expf(cum) * inv_denom;
    const size_t idx = ((size_t)(t0 + i) * B_DIM + b) * N_DIM + n;
    w[idx] = kk[idx] * decay;
  }
}

// ---------------------------------------------------------------------------
// Kernel 2: cumulative outer-product sum.
// Block = one (b,d) pair (512 blocks), 64 threads, lane = n.
//   acc[n] += v[t,b,d] * w[t,b,n];  out[t,b,d,n] = acc[n]
// Lane-consecutive n -> 256B contiguous wave loads (L2-hit) and stores (HBM).
// ---------------------------------------------------------------------------
__global__ __launch_bounds__(64) void scan_outer_kernel(
    const float* __restrict__ v, const float* __restrict__ w,
    float* __restrict__ out) {
  const int b = blockIdx.x >> 6;  // 0..7
  const int d = blockIdx.x & 63;  // 0..63
  const int n = threadIdx.x;      // 0..63

  const float* __restrict__ wp = w + (size_t)b * N_DIM + n;
  const float* __restrict__ vp = v + (size_t)b * D_DIM + d;
  float* __restrict__ op = out + ((size_t)b * D_DIM + d) * N_DIM + n;

  float acc = 0.f;
#pragma unroll 8
  for (int t = 0; t < T_DIM; ++t) {
    const float vv = vp[(size_t)t * (B_DIM * D_DIM)];
    const float ww = wp[(size_t)t * (B_DIM * N_DIM)];
    acc = fmaf(vv, ww, acc);
    op[(size_t)t * ((size_t)B_DIM * D_DIM * N_DIM)] = acc;
  }
}

// ---------------------------------------------------------------------------
extern "C" void kernel_launch(void* const* d_in, const int* in_sizes, int n_in,
                              void* d_out, int out_size, void* d_ws, size_t ws_size,
                              hipStream_t stream) {
  const float* v     = (const float*)d_in[0];
  const float* k     = (const float*)d_in[1];
  const float* alpha = (const float*)d_in[2];
  float* out = (float*)d_out;
  float* w   = (float*)d_ws;  // needs T*B*n*4 = 2 MiB of scratch

  decay_w_kernel<<<B_DIM * N_DIM, 256, 0, stream>>>(k, alpha, w);
  scan_outer_kernel<<<B_DIM * D_DIM, 64, 0, stream>>>(v, w, out);
}

// Round 2
// 161.457 us; speedup vs baseline: 1.4693x; 1.4693x over previous
//
#include <hip/hip_runtime.h>

// Problem dims (fixed by setup_inputs): T=1024, B=8, d=64, n=64
#define T_DIM 1024
#define B_DIM 8
#define D_DIM 64
#define N_DIM 64

// Decay scan chunking: 64 chunks of 16 timesteps
#define DC_CHUNKS 64
#define DC_LEN 16

// Outer-product cumsum chunking: 16 chunks of 64 timesteps
#define SC_CHUNKS 16
#define SC_LEN 64

// Workspace layout (floats):
//   w    : [T][B][N]            at 0          (524288 floats, 2 MB)
//   lsum : [B][DC_CHUNKS][N]    at 524288     (32768 floats, 128 KB)
//   psum : [SC_CHUNKS][B][D][N] at 557056     (524288 floats, 2 MB)
#define WS_W 0
#define WS_LSUM 524288
#define WS_PSUM 557056

// ---------------------------------------------------------------------------
// D1: per-(b, t-chunk) sums of log(max(alpha,1e-8)) along t. lane = n.
// Every load is a contiguous 256B row alpha[t][b][:].
// ---------------------------------------------------------------------------
__global__ __launch_bounds__(64) void decay_chunksum_kernel(
    const float* __restrict__ alpha, float* __restrict__ ws) {
  const int b = blockIdx.x >> 6;   // 0..7
  const int c = blockIdx.x & 63;   // 0..63
  const int n = threadIdx.x;

  float s = 0.f;
#pragma unroll
  for (int i = 0; i < DC_LEN; ++i) {
    const int t = c * DC_LEN + i;
    const float a = alpha[((size_t)t * B_DIM + b) * N_DIM + n];
    s += logf(fmaxf(a, 1e-8f));
  }
  ws[WS_LSUM + ((size_t)b * DC_CHUNKS + c) * N_DIM + n] = s;
}

// ---------------------------------------------------------------------------
// D2: per-(b, t-chunk) block: gather chunk prefix + grand total from lsum,
// then recompute in-chunk log-prefix and emit w[t,b,n] = k * decay.
// ---------------------------------------------------------------------------
__global__ __launch_bounds__(64) void decay_w_kernel(
    const float* __restrict__ alpha, const float* __restrict__ kk,
    float* __restrict__ ws) {
  const int b = blockIdx.x >> 6;
  const int c = blockIdx.x & 63;
  const int n = threadIdx.x;

  const float* __restrict__ lsum = ws + WS_LSUM + (size_t)b * DC_CHUNKS * N_DIM + n;
  float pre = 0.f, tot = 0.f;
#pragma unroll 8
  for (int j = 0; j < DC_CHUNKS; ++j) {
    const float sj = lsum[(size_t)j * N_DIM];
    pre += (j < c) ? sj : 0.f;
    tot += sj;
  }

  // Matches reference f32 numerics: expf(tot) underflows -> denom = 1e-8
  const float invden = 1.0f / (expf(tot) + 1e-8f);

  float cum = pre;
#pragma unroll
  for (int i = 0; i < DC_LEN; ++i) {
    const int t = c * DC_LEN + i;
    const size_t idx = ((size_t)t * B_DIM + b) * N_DIM + n;
    cum += logf(fmaxf(alpha[idx], 1e-8f));
    ws[WS_W + idx] = kk[idx] * expf(cum) * invden;
  }
}

// ---------------------------------------------------------------------------
// S1: per-chunk partial sums of v[t,b,d]*w[t,b,n].
// Block = (c, b, d-tile of 16). Thread: d_loc = tid>>4, n0 = (tid&15)*4.
// ---------------------------------------------------------------------------
__global__ __launch_bounds__(256) void chunk_psum_kernel(
    const float* __restrict__ v, const float* __restrict__ ws_in,
    float* __restrict__ ws_out) {
  const int bid = blockIdx.x;
  const int dt = bid & 3;          // d-tile 0..3
  const int b  = (bid >> 2) & 7;   // 0..7
  const int c  = bid >> 5;         // 0..15
  const int tid = threadIdx.x;
  const int d  = dt * 16 + (tid >> 4);
  const int n0 = (tid & 15) * 4;

  const float* __restrict__ vp = v + (size_t)b * D_DIM + d;
  const float* __restrict__ wp = ws_in + WS_W + (size_t)b * N_DIM + n0;

  float4 a0 = {0,0,0,0}, a1 = {0,0,0,0}, a2 = {0,0,0,0}, a3 = {0,0,0,0};
#pragma unroll 4
  for (int i = 0; i < SC_LEN; i += 4) {
    const int t = c * SC_LEN + i;
#pragma unroll
    for (int u = 0; u < 4; ++u) {
      const float vv = vp[(size_t)(t + u) * (B_DIM * D_DIM)];
      const float4 w4 = *(const float4*)(wp + (size_t)(t + u) * (B_DIM * N_DIM));
      float4& acc = (u == 0) ? a0 : (u == 1) ? a1 : (u == 2) ? a2 : a3;
      acc.x = fmaf(vv, w4.x, acc.x);
      acc.y = fmaf(vv, w4.y, acc.y);
      acc.z = fmaf(vv, w4.z, acc.z);
      acc.w = fmaf(vv, w4.w, acc.w);
    }
  }
  float4 s;
  s.x = (a0.x + a1.x) + (a2.x + a3.x);
  s.y = (a0.y + a1.y) + (a2.y + a3.y);
  s.z = (a0.z + a1.z) + (a2.z + a3.z);
  s.w = (a0.w + a1.w) + (a2.w + a3.w);
  *(float4*)(ws_out + WS_PSUM +
             (((size_t)c * B_DIM + b) * D_DIM + d) * N_DIM + n0) = s;
}

// ---------------------------------------------------------------------------
// S2: final. acc = sum of prior chunk psums, then 64-step store loop.
// Wave stores 4x256B contiguous (1KB) per step.
// ---------------------------------------------------------------------------
__global__ __launch_bounds__(256) void scan_store_kernel(
    const float* __restrict__ v, const float* __restrict__ ws,
    float* __restrict__ out) {
  const int bid = blockIdx.x;
  const int dt = bid & 3;
  const int b  = (bid >> 2) & 7;
  const int c  = bid >> 5;
  const int tid = threadIdx.x;
  const int d  = dt * 16 + (tid >> 4);
  const int n0 = (tid & 15) * 4;

  const float* __restrict__ vp = v + (size_t)b * D_DIM + d;
  const float* __restrict__ wp = ws + WS_W + (size_t)b * N_DIM + n0;
  const float* __restrict__ pp = ws + WS_PSUM + ((size_t)b * D_DIM + d) * N_DIM + n0;

  float4 acc = {0,0,0,0};
  for (int j = 0; j < c; ++j) {
    const float4 p = *(const float4*)(pp + (size_t)j * (B_DIM * D_DIM * N_DIM));
    acc.x += p.x; acc.y += p.y; acc.z += p.z; acc.w += p.w;
  }

#pragma unroll 8
  for (int i = 0; i < SC_LEN; ++i) {
    const int t = c * SC_LEN + i;
    const float vv = vp[(size_t)t * (B_DIM * D_DIM)];
    const float4 w4 = *(const float4*)(wp + (size_t)t * (B_DIM * N_DIM));
    acc.x = fmaf(vv, w4.x, acc.x);
    acc.y = fmaf(vv, w4.y, acc.y);
    acc.z = fmaf(vv, w4.z, acc.z);
    acc.w = fmaf(vv, w4.w, acc.w);
    *(float4*)(out + (((size_t)t * B_DIM + b) * D_DIM + d) * N_DIM + n0) = acc;
  }
}

// ---------------------------------------------------------------------------
extern "C" void kernel_launch(void* const* d_in, const int* in_sizes, int n_in,
                              void* d_out, int out_size, void* d_ws, size_t ws_size,
                              hipStream_t stream) {
  const float* v     = (const float*)d_in[0];
  const float* k     = (const float*)d_in[1];
  const float* alpha = (const float*)d_in[2];
  float* out = (float*)d_out;
  float* ws  = (float*)d_ws;  // needs ~4.33 MB

  decay_chunksum_kernel<<<B_DIM * DC_CHUNKS, 64, 0, stream>>>(alpha, ws);
  decay_w_kernel<<<B_DIM * DC_CHUNKS, 64, 0, stream>>>(alpha, k, ws);
  chunk_psum_kernel<<<SC_CHUNKS * B_DIM * 4, 256, 0, stream>>>(v, ws, ws);
  scan_store_kernel<<<SC_CHUNKS * B_DIM * 4, 256, 0, stream>>>(v, ws, out);
}